// Round 1
// baseline (1616.969 us; speedup 1.0000x reference)
//
#include <hip/hip_runtime.h>
#include <cstdint>

#define NROI 2048
#define NCLS 21
#define NFG  20

// ---- sortable key helpers -------------------------------------------------
// desc_key(s): larger float -> smaller uint, so ascending u64 sort ==
// (score descending, index ascending) when index is in the low 32 bits.
__device__ __forceinline__ unsigned int desc_key(float s) {
  unsigned int u = __float_as_uint(s);
  unsigned int asc = (u & 0x80000000u) ? ~u : (u | 0x80000000u);
  return ~asc;
}
__device__ __forceinline__ float key_to_float(unsigned int desc) {
  unsigned int asc = ~desc;
  unsigned int u = (asc & 0x80000000u) ? (asc ^ 0x80000000u) : ~asc;
  return __uint_as_float(u);
}

__device__ __forceinline__ unsigned long long shfl_down_u64(unsigned long long v, int off) {
  unsigned int lo = (unsigned int)(v & 0xFFFFFFFFull);
  unsigned int hi = (unsigned int)(v >> 32);
  lo = __shfl_down(lo, off);
  hi = __shfl_down(hi, off);
  return ((unsigned long long)hi << 32) | (unsigned long long)lo;
}

// ---- phase 1: softmax + argmax + box decode -------------------------------
__global__ __launch_bounds__(256)
void k_decode(const float* __restrict__ rois,
              const float* __restrict__ locs,
              const float* __restrict__ scores,
              float* __restrict__ probs,
              float* __restrict__ decoded,
              unsigned int* __restrict__ counter) {
  int r = blockIdx.x * blockDim.x + threadIdx.x;
  if (r == 0) *counter = 0u;   // reset candidate counter each launch
  if (r >= NROI) return;

  float s[NCLS];
  float m = scores[r * NCLS];
  #pragma unroll
  for (int c = 0; c < NCLS; ++c) { s[c] = scores[r * NCLS + c]; m = fmaxf(m, s[c]); }
  float e[NCLS]; float sum = 0.0f;
  #pragma unroll
  for (int c = 0; c < NCLS; ++c) { e[c] = expf(s[c] - m); sum += e[c]; }

  float p0 = e[0] / sum;
  probs[r * NCLS] = p0;
  int best = 0; float pb = p0;
  #pragma unroll
  for (int c = 1; c < NCLS; ++c) {
    float p = e[c] / sum;
    probs[r * NCLS + c] = p;
    if (p > pb) { pb = p; best = c; }   // strict > keeps first index (argmax semantics)
  }

  float x0 = rois[r * 4 + 0], y0 = rois[r * 4 + 1];
  float x1 = rois[r * 4 + 2], y1 = rois[r * 4 + 3];
  float pcx = __fmul_rn(__fadd_rn(x0, x1), 0.5f);
  float pcy = __fmul_rn(__fadd_rn(y0, y1), 0.5f);
  float pw  = __fsub_rn(x1, x0);
  float ph  = __fsub_rn(y1, y0);

  const float* g = locs + r * (NCLS * 4) + best * 4;
  float g0 = g[0] / 10.0f;
  float g1 = g[1] / 10.0f;
  float g2 = g[2] / 20.0f;
  float g3 = g[3] / 20.0f;

  // no-FMA-contraction decode to match numpy rounding
  float cx = __fadd_rn(__fmul_rn(g0, pw), pcx);
  float cy = __fadd_rn(__fmul_rn(g1, ph), pcy);
  float w  = __fmul_rn(expf(g2), pw);
  float h  = __fmul_rn(expf(g3), ph);
  float hw = __fmul_rn(w, 0.5f);
  float hh = __fmul_rn(h, 0.5f);
  decoded[r * 4 + 0] = __fsub_rn(cx, hw);
  decoded[r * 4 + 1] = __fsub_rn(cy, hh);
  decoded[r * 4 + 2] = __fadd_rn(cx, hw);
  decoded[r * 4 + 3] = __fadd_rn(cy, hh);
}

// ---- phase 2: per-class sort + greedy NMS ---------------------------------
__global__ __launch_bounds__(256)
void k_nms(const float* __restrict__ probs,
           const float* __restrict__ decoded,
           const float* __restrict__ min_score_p,
           const float* __restrict__ max_overlap_p,
           int* __restrict__ idx_all,
           unsigned long long* __restrict__ cand,
           unsigned int* __restrict__ counter) {
  __shared__ unsigned long long keys[NROI];              // 16 KB
  __shared__ float sbx0[NROI], sby0[NROI], sbx1[NROI], sby1[NROI]; // 32 KB
  __shared__ float ss[NROI];                             // 8 KB
  __shared__ unsigned char sup[NROI];                    // 2 KB

  const int cls = blockIdx.x;       // foreground class 0..19 -> prob column cls+1
  const int tid = threadIdx.x;
  const float msc = *min_score_p;
  const float ovr = *max_overlap_p;

  for (int i = tid; i < NROI; i += 256) {
    float s = probs[i * NCLS + cls + 1];
    float keyf = (s > msc) ? s : -__builtin_inff();
    keys[i] = ((unsigned long long)desc_key(keyf) << 32) | (unsigned int)i;
  }
  __syncthreads();

  // bitonic sort, ascending in key64 => score desc, index asc (stable-equivalent)
  for (int k = 2; k <= NROI; k <<= 1) {
    for (int j = k >> 1; j > 0; j >>= 1) {
      for (int i = tid; i < NROI; i += 256) {
        int ixj = i ^ j;
        if (ixj > i) {
          unsigned long long a = keys[i], b = keys[ixj];
          bool up = ((i & k) == 0);
          if ((a > b) == up) { keys[i] = b; keys[ixj] = a; }
        }
      }
      __syncthreads();
    }
  }

  for (int i = tid; i < NROI; i += 256) {
    int orig = (int)(keys[i] & 0xFFFFFFFFu);
    float s = probs[orig * NCLS + cls + 1];
    ss[i]  = s;
    sup[i] = (s > msc) ? (unsigned char)0 : (unsigned char)1; // invalid start suppressed
    sbx0[i] = decoded[orig * 4 + 0];
    sby0[i] = decoded[orig * 4 + 1];
    sbx1[i] = decoded[orig * 4 + 2];
    sby1[i] = decoded[orig * 4 + 3];
    idx_all[cls * NROI + i] = orig;
  }

  // greedy sequential NMS over sorted order
  for (int i = 0; i < NROI; ++i) {
    __syncthreads();                 // publish previous iteration's sup writes
    if (sup[i]) continue;            // uniform across block
    float ax0 = sbx0[i], ay0 = sby0[i], ax1 = sbx1[i], ay1 = sby1[i];
    float area_a = __fmul_rn(__fsub_rn(ax1, ax0), __fsub_rn(ay1, ay0));
    for (int j = tid; j < NROI; j += 256) {
      if (j == i || sup[j]) continue;
      float lx = fmaxf(ax0, sbx0[j]);
      float ly = fmaxf(ay0, sby0[j]);
      float rx = fminf(ax1, sbx1[j]);
      float ry = fminf(ay1, sby1[j]);
      float w = fmaxf(__fsub_rn(rx, lx), 0.0f);
      float h = fmaxf(__fsub_rn(ry, ly), 0.0f);
      float inter = __fmul_rn(w, h);
      float areab = __fmul_rn(__fsub_rn(sbx1[j], sbx0[j]), __fsub_rn(sby1[j], sby0[j]));
      float iou = __fdiv_rn(inter, __fsub_rn(__fadd_rn(area_a, areab), inter));
      if (iou > ovr) sup[j] = 1;
    }
  }
  __syncthreads();

  // compact surviving candidates (order nondeterministic; keys unique -> topk deterministic)
  for (int i = tid; i < NROI; i += 256) {
    if (!sup[i]) {
      unsigned int pos = atomicAdd(counter, 1u);
      unsigned int flat = (unsigned int)(cls * NROI + i);
      cand[pos] = ((unsigned long long)desc_key(ss[i]) << 32) | flat;
    }
  }
}

// ---- phase 3: global top-K ------------------------------------------------
__global__ __launch_bounds__(256)
void k_topk(unsigned long long* __restrict__ cand,
            const unsigned int* __restrict__ counter,
            const int* __restrict__ idx_all,
            const float* __restrict__ decoded,
            float* __restrict__ out,
            const int* __restrict__ top_k_p) {
  const int M = (int)*counter;
  const int K = *top_k_p;
  __shared__ unsigned long long wmin[4];
  __shared__ unsigned long long sbest;
  const int tid = threadIdx.x;

  for (int r = 0; r < K; ++r) {
    unsigned long long lmin = ~0ULL;
    for (int j = tid; j < M; j += 256) {
      unsigned long long v = cand[j];
      if (v < lmin) lmin = v;
    }
    #pragma unroll
    for (int off = 32; off > 0; off >>= 1) {
      unsigned long long o = shfl_down_u64(lmin, off);
      if (o < lmin) lmin = o;
    }
    if ((tid & 63) == 0) wmin[tid >> 6] = lmin;
    __syncthreads();
    if (tid == 0) {
      unsigned long long b = wmin[0];
      #pragma unroll
      for (int w = 1; w < 4; ++w) if (wmin[w] < b) b = wmin[w];
      sbest = b;
    }
    __syncthreads();
    unsigned long long b = sbest;
    if (b != ~0ULL) {
      for (int j = tid; j < M; j += 256)
        if (cand[j] == b) cand[j] = ~0ULL;   // remove selected (each thread owns its j's)
    }
    if (tid == 0) {
      if (b != ~0ULL) {
        unsigned int flat = (unsigned int)(b & 0xFFFFFFFFu);
        float score = key_to_float((unsigned int)(b >> 32));
        int cls = (int)(flat >> 11);         // /2048
        int orig = idx_all[flat];
        out[r * 4 + 0] = decoded[orig * 4 + 0];
        out[r * 4 + 1] = decoded[orig * 4 + 1];
        out[r * 4 + 2] = decoded[orig * 4 + 2];
        out[r * 4 + 3] = decoded[orig * 4 + 3];
        out[K * 4 + r] = (float)(cls + 1);
        out[K * 5 + r] = score;
      } else {
        out[r * 4 + 0] = 0.0f; out[r * 4 + 1] = 0.0f;
        out[r * 4 + 2] = 1.0f; out[r * 4 + 3] = 1.0f;
        out[K * 4 + r] = 0.0f;
        out[K * 5 + r] = 0.0f;
      }
    }
    __syncthreads();
  }
}

// ---- launch ---------------------------------------------------------------
extern "C" void kernel_launch(void* const* d_in, const int* in_sizes, int n_in,
                              void* d_out, int out_size, void* d_ws, size_t ws_size,
                              hipStream_t stream) {
  const float* rois        = (const float*)d_in[0];
  const float* locs        = (const float*)d_in[1];
  const float* scores      = (const float*)d_in[2];
  const float* min_score   = (const float*)d_in[3];
  const float* max_overlap = (const float*)d_in[4];
  const int*   top_k       = (const int*)d_in[5];

  char* ws = (char*)d_ws;
  // layout: counter(8) | probs 2048*21*4 | decoded 2048*4*4 | idx_all 20*2048*4 | cand 20*2048*8
  unsigned int* counter = (unsigned int*)ws;
  float* probs   = (float*)(ws + 8);
  float* decoded = (float*)(ws + 8 + NROI * NCLS * 4);
  int*   idx_all = (int*)(ws + 8 + NROI * NCLS * 4 + NROI * 4 * 4);
  unsigned long long* cand =
      (unsigned long long*)(ws + 8 + NROI * NCLS * 4 + NROI * 4 * 4 + NFG * NROI * 4);

  k_decode<<<NROI / 256, 256, 0, stream>>>(rois, locs, scores, probs, decoded, counter);
  k_nms<<<NFG, 256, 0, stream>>>(probs, decoded, min_score, max_overlap, idx_all, cand, counter);
  k_topk<<<1, 256, 0, stream>>>(cand, counter, idx_all, decoded, (float*)d_out, top_k);
}

// Round 2
// 422.096 us; speedup vs baseline: 3.8308x; 3.8308x over previous
//
#include <hip/hip_runtime.h>
#include <cstdint>

#define NROI 2048
#define NCLS 21
#define NFG  20
#define CPAD 128          // candidate slots kept per class (>= top_k)
#define CTOT (NFG * CPAD) // 2560
#define CSRT 4096         // bitonic size for final top-k sort

// ---- sortable key helpers -------------------------------------------------
// desc_key(s): larger float -> smaller uint, so ascending u64 sort ==
// (score descending, index ascending) when index is in the low 32 bits.
__device__ __forceinline__ unsigned int desc_key(float s) {
  unsigned int u = __float_as_uint(s);
  unsigned int asc = (u & 0x80000000u) ? ~u : (u | 0x80000000u);
  return ~asc;
}
__device__ __forceinline__ float key_to_float(unsigned int desc) {
  unsigned int asc = ~desc;
  unsigned int u = (asc & 0x80000000u) ? (asc ^ 0x80000000u) : ~asc;
  return __uint_as_float(u);
}

__device__ __forceinline__ unsigned long long shfl_u64(unsigned long long v, int src) {
  unsigned int lo = (unsigned int)(v & 0xFFFFFFFFull);
  unsigned int hi = (unsigned int)(v >> 32);
  lo = __shfl(lo, src);
  hi = __shfl(hi, src);
  return ((unsigned long long)hi << 32) | (unsigned long long)lo;
}
__device__ __forceinline__ unsigned long long shfl_down_u64(unsigned long long v, int off) {
  unsigned int lo = (unsigned int)(v & 0xFFFFFFFFull);
  unsigned int hi = (unsigned int)(v >> 32);
  lo = __shfl_down(lo, off);
  hi = __shfl_down(hi, off);
  return ((unsigned long long)hi << 32) | (unsigned long long)lo;
}

// ---- phase 1: softmax + argmax + box decode -------------------------------
__global__ __launch_bounds__(256)
void k_decode(const float* __restrict__ rois,
              const float* __restrict__ locs,
              const float* __restrict__ scores,
              float* __restrict__ probs,
              float* __restrict__ decoded,
              unsigned int* __restrict__ counter) {
  int r = blockIdx.x * blockDim.x + threadIdx.x;
  if (r == 0) *counter = 0u;   // old-path candidate counter reset (harmless for new path)
  if (r >= NROI) return;

  float s[NCLS];
  float m = scores[r * NCLS];
  #pragma unroll
  for (int c = 0; c < NCLS; ++c) { s[c] = scores[r * NCLS + c]; m = fmaxf(m, s[c]); }
  float e[NCLS]; float sum = 0.0f;
  #pragma unroll
  for (int c = 0; c < NCLS; ++c) { e[c] = expf(s[c] - m); sum += e[c]; }

  float p0 = e[0] / sum;
  probs[r * NCLS] = p0;
  int best = 0; float pb = p0;
  #pragma unroll
  for (int c = 1; c < NCLS; ++c) {
    float p = e[c] / sum;
    probs[r * NCLS + c] = p;
    if (p > pb) { pb = p; best = c; }   // strict > keeps first index (argmax semantics)
  }

  float x0 = rois[r * 4 + 0], y0 = rois[r * 4 + 1];
  float x1 = rois[r * 4 + 2], y1 = rois[r * 4 + 3];
  float pcx = __fmul_rn(__fadd_rn(x0, x1), 0.5f);
  float pcy = __fmul_rn(__fadd_rn(y0, y1), 0.5f);
  float pw  = __fsub_rn(x1, x0);
  float ph  = __fsub_rn(y1, y0);

  const float* g = locs + r * (NCLS * 4) + best * 4;
  float g0 = g[0] / 10.0f;
  float g1 = g[1] / 10.0f;
  float g2 = g[2] / 20.0f;
  float g3 = g[3] / 20.0f;

  // no-FMA-contraction decode to match numpy rounding
  float cx = __fadd_rn(__fmul_rn(g0, pw), pcx);
  float cy = __fadd_rn(__fmul_rn(g1, ph), pcy);
  float w  = __fmul_rn(expf(g2), pw);
  float h  = __fmul_rn(expf(g3), ph);
  float hw = __fmul_rn(w, 0.5f);
  float hh = __fmul_rn(h, 0.5f);
  decoded[r * 4 + 0] = __fsub_rn(cx, hw);
  decoded[r * 4 + 1] = __fsub_rn(cy, hh);
  decoded[r * 4 + 2] = __fadd_rn(cx, hw);
  decoded[r * 4 + 3] = __fadd_rn(cy, hh);
}

// ---- phase 2a: per-class sort (score desc, index asc) ---------------------
__global__ __launch_bounds__(256)
void k_sort(const float* __restrict__ probs,
            const float* __restrict__ decoded,
            const float* __restrict__ min_score_p,
            unsigned long long* __restrict__ skey,
            float* __restrict__ sbox,
            int* __restrict__ nvalid,
            unsigned long long* __restrict__ cand) {
  __shared__ unsigned long long keys[NROI];   // 16 KB
  __shared__ int cnt;
  const int cls = blockIdx.x;
  const int tid = threadIdx.x;
  if (tid == 0) cnt = 0;
  __syncthreads();
  const float msc = *min_score_p;

  int local = 0;
  for (int i = tid; i < NROI; i += 256) {
    float s = probs[i * NCLS + cls + 1];
    bool valid = s > msc;
    local += valid ? 1 : 0;
    float keyf = valid ? s : -__builtin_inff();
    keys[i] = ((unsigned long long)desc_key(keyf) << 32) | (unsigned int)i;
  }
  atomicAdd(&cnt, local);
  __syncthreads();

  // bitonic sort ascending => score desc, orig index asc (stable-equivalent)
  for (int k = 2; k <= NROI; k <<= 1) {
    for (int j = k >> 1; j > 0; j >>= 1) {
      for (int i = tid; i < NROI; i += 256) {
        int ixj = i ^ j;
        if (ixj > i) {
          unsigned long long a = keys[i], b = keys[ixj];
          bool up = ((i & k) == 0);
          if ((a > b) == up) { keys[i] = b; keys[ixj] = a; }
        }
      }
      __syncthreads();
    }
  }

  for (int i = tid; i < NROI; i += 256) {
    unsigned long long key = keys[i];
    int orig = (int)(key & 0xFFFFFFFFu);
    skey[(size_t)cls * NROI + i] = key;
    size_t o = ((size_t)cls * NROI + i) * 4;
    sbox[o + 0] = decoded[orig * 4 + 0];
    sbox[o + 1] = decoded[orig * 4 + 1];
    sbox[o + 2] = decoded[orig * 4 + 2];
    sbox[o + 3] = decoded[orig * 4 + 3];
  }
  if (tid < CPAD) cand[cls * CPAD + tid] = ~0ULL;   // pad slots
  if (tid == 0) nvalid[cls] = cnt;
}

// ---- phase 2b: suppression bitmask (upper triangle, j > i) ----------------
// grid: NFG * 256 blocks of 256 threads; each thread -> one (row i, word w).
__global__ __launch_bounds__(256)
void k_mask(const float* __restrict__ sbox,
            const float* __restrict__ max_overlap_p,
            const int* __restrict__ nvalid,
            unsigned long long* __restrict__ mask) {
  __shared__ float bx0[NROI], by0[NROI], bx1[NROI], by1[NROI]; // 32 KB
  const int cls = blockIdx.x >> 8;
  const int chunk = blockIdx.x & 255;
  const int tid = threadIdx.x;
  const float ovr = *max_overlap_p;
  const int nv = nvalid[cls];

  const float* cb = sbox + (size_t)cls * NROI * 4;
  for (int j = tid; j < NROI; j += 256) {
    bx0[j] = cb[j * 4 + 0];
    by0[j] = cb[j * 4 + 1];
    bx1[j] = cb[j * 4 + 2];
    by1[j] = cb[j * 4 + 3];
  }
  __syncthreads();

  int e = chunk * 256 + tid;
  int i = e >> 5;          // sorted row
  int w = e & 31;          // 64-bit word of columns
  int jbase = w * 64;
  unsigned long long m = 0;

  if (i < nv && jbase + 63 > i) {
    float ax0 = bx0[i], ay0 = by0[i], ax1 = bx1[i], ay1 = by1[i];
    float area_a = __fmul_rn(__fsub_rn(ax1, ax0), __fsub_rn(ay1, ay0));
    for (int bb = 0; bb < 64; ++bb) {
      int b = (bb + tid) & 63;        // stagger LDS reads across banks
      int j = jbase + b;
      if (j > i && j < nv) {
        float lx = fmaxf(ax0, bx0[j]);
        float ly = fmaxf(ay0, by0[j]);
        float rx = fminf(ax1, bx1[j]);
        float ry = fminf(ay1, by1[j]);
        float ww = fmaxf(__fsub_rn(rx, lx), 0.0f);
        float hh = fmaxf(__fsub_rn(ry, ly), 0.0f);
        float inter = __fmul_rn(ww, hh);
        float areab = __fmul_rn(__fsub_rn(bx1[j], bx0[j]), __fsub_rn(by1[j], by0[j]));
        float iou = __fdiv_rn(inter, __fsub_rn(__fadd_rn(area_a, areab), inter));
        if (iou > ovr) m |= 1ULL << b;
      }
    }
  }
  mask[((size_t)cls * NROI + i) * 32 + w] = m;
}

// ---- phase 2c: single-wave greedy sweep + compaction ----------------------
__global__ __launch_bounds__(64)
void k_sweep(const unsigned long long* __restrict__ mask,
             const unsigned long long* __restrict__ skey,
             const int* __restrict__ nvalid,
             unsigned long long* __restrict__ cand) {
  const int cls = blockIdx.x;
  const int lane = threadIdx.x;
  const int l = lane & 31;          // owned removed-word index
  const int nv = nvalid[cls];

  unsigned long long removed;
  {
    int start = nv - l * 64;        // rows >= nvalid start suppressed
    removed = (start <= 0) ? ~0ULL : ((start >= 64) ? 0ULL : (~0ULL << start));
  }

  const unsigned long long* mrow = mask + (size_t)cls * NROI * 32;
  for (int base = 0; base < NROI; base += 16) {
    unsigned long long m[16];
    #pragma unroll
    for (int k = 0; k < 16; ++k)
      m[k] = (lane < 32) ? mrow[(size_t)(base + k) * 32 + lane] : 0ULL;
    #pragma unroll
    for (int k = 0; k < 16; ++k) {
      int i = base + k;
      unsigned long long rw = shfl_u64(removed, i >> 6);   // wave-uniform
      if (!((rw >> (i & 63)) & 1ULL)) removed |= m[k];
    }
  }

  if (lane < 32) {
    unsigned long long surv = ~removed;
    int cnt = __popcll(surv);
    int pre = cnt;
    #pragma unroll
    for (int off = 1; off < 32; off <<= 1) {
      int v = __shfl_up(pre, off);
      if (l >= off) pre += v;
    }
    int rank = pre - cnt;           // exclusive prefix
    unsigned long long s = surv;
    while (s) {
      int b = __ffsll((long long)s) - 1;
      s &= s - 1;
      if (rank < CPAD) {
        int i = l * 64 + b;
        unsigned long long key = skey[(size_t)cls * NROI + i];
        cand[cls * CPAD + rank] =
            (key & 0xFFFFFFFF00000000ULL) | (unsigned int)(cls * NROI + i);
      }
      ++rank;
    }
  }
}

// ---- phase 3: sort 2560 candidates, emit top-K ----------------------------
__global__ __launch_bounds__(256)
void k_topk2(const unsigned long long* __restrict__ cand,
             const float* __restrict__ sbox,
             float* __restrict__ out,
             const int* __restrict__ top_k_p) {
  __shared__ unsigned long long keys[CSRT];   // 32 KB
  const int tid = threadIdx.x;
  for (int t = tid; t < CSRT; t += 256)
    keys[t] = (t < CTOT) ? cand[t] : ~0ULL;
  __syncthreads();

  for (int k = 2; k <= CSRT; k <<= 1) {
    for (int j = k >> 1; j > 0; j >>= 1) {
      for (int t = tid; t < CSRT; t += 256) {
        int ixj = t ^ j;
        if (ixj > t) {
          unsigned long long a = keys[t], b = keys[ixj];
          bool up = ((t & k) == 0);
          if ((a > b) == up) { keys[t] = b; keys[ixj] = a; }
        }
      }
      __syncthreads();
    }
  }

  const int K = *top_k_p;
  for (int r = tid; r < K; r += 256) {
    unsigned long long key = keys[r];
    if (key != ~0ULL) {
      unsigned int flat = (unsigned int)(key & 0xFFFFFFFFu);
      float score = key_to_float((unsigned int)(key >> 32));
      int cls = (int)(flat >> 11);             // /2048
      out[r * 4 + 0] = sbox[(size_t)flat * 4 + 0];
      out[r * 4 + 1] = sbox[(size_t)flat * 4 + 1];
      out[r * 4 + 2] = sbox[(size_t)flat * 4 + 2];
      out[r * 4 + 3] = sbox[(size_t)flat * 4 + 3];
      out[K * 4 + r] = (float)(cls + 1);
      out[K * 5 + r] = score;
    } else {
      out[r * 4 + 0] = 0.0f; out[r * 4 + 1] = 0.0f;
      out[r * 4 + 2] = 1.0f; out[r * 4 + 3] = 1.0f;
      out[K * 4 + r] = 0.0f;
      out[K * 5 + r] = 0.0f;
    }
  }
}

// ======================== OLD (fallback) PATH ==============================
__global__ __launch_bounds__(256)
void k_nms_old(const float* __restrict__ probs,
               const float* __restrict__ decoded,
               const float* __restrict__ min_score_p,
               const float* __restrict__ max_overlap_p,
               int* __restrict__ idx_all,
               unsigned long long* __restrict__ cand,
               unsigned int* __restrict__ counter) {
  __shared__ unsigned long long keys[NROI];
  __shared__ float sbx0[NROI], sby0[NROI], sbx1[NROI], sby1[NROI];
  __shared__ float ss[NROI];
  __shared__ unsigned char sup[NROI];

  const int cls = blockIdx.x;
  const int tid = threadIdx.x;
  const float msc = *min_score_p;
  const float ovr = *max_overlap_p;

  for (int i = tid; i < NROI; i += 256) {
    float s = probs[i * NCLS + cls + 1];
    float keyf = (s > msc) ? s : -__builtin_inff();
    keys[i] = ((unsigned long long)desc_key(keyf) << 32) | (unsigned int)i;
  }
  __syncthreads();
  for (int k = 2; k <= NROI; k <<= 1) {
    for (int j = k >> 1; j > 0; j >>= 1) {
      for (int i = tid; i < NROI; i += 256) {
        int ixj = i ^ j;
        if (ixj > i) {
          unsigned long long a = keys[i], b = keys[ixj];
          bool up = ((i & k) == 0);
          if ((a > b) == up) { keys[i] = b; keys[ixj] = a; }
        }
      }
      __syncthreads();
    }
  }
  for (int i = tid; i < NROI; i += 256) {
    int orig = (int)(keys[i] & 0xFFFFFFFFu);
    float s = probs[orig * NCLS + cls + 1];
    ss[i]  = s;
    sup[i] = (s > msc) ? (unsigned char)0 : (unsigned char)1;
    sbx0[i] = decoded[orig * 4 + 0];
    sby0[i] = decoded[orig * 4 + 1];
    sbx1[i] = decoded[orig * 4 + 2];
    sby1[i] = decoded[orig * 4 + 3];
    idx_all[cls * NROI + i] = orig;
  }
  for (int i = 0; i < NROI; ++i) {
    __syncthreads();
    if (sup[i]) continue;
    float ax0 = sbx0[i], ay0 = sby0[i], ax1 = sbx1[i], ay1 = sby1[i];
    float area_a = __fmul_rn(__fsub_rn(ax1, ax0), __fsub_rn(ay1, ay0));
    for (int j = tid; j < NROI; j += 256) {
      if (j == i || sup[j]) continue;
      float lx = fmaxf(ax0, sbx0[j]);
      float ly = fmaxf(ay0, sby0[j]);
      float rx = fminf(ax1, sbx1[j]);
      float ry = fminf(ay1, sby1[j]);
      float w = fmaxf(__fsub_rn(rx, lx), 0.0f);
      float h = fmaxf(__fsub_rn(ry, ly), 0.0f);
      float inter = __fmul_rn(w, h);
      float areab = __fmul_rn(__fsub_rn(sbx1[j], sbx0[j]), __fsub_rn(sby1[j], sby0[j]));
      float iou = __fdiv_rn(inter, __fsub_rn(__fadd_rn(area_a, areab), inter));
      if (iou > ovr) sup[j] = 1;
    }
  }
  __syncthreads();
  for (int i = tid; i < NROI; i += 256) {
    if (!sup[i]) {
      unsigned int pos = atomicAdd(counter, 1u);
      unsigned int flat = (unsigned int)(cls * NROI + i);
      cand[pos] = ((unsigned long long)desc_key(ss[i]) << 32) | flat;
    }
  }
}

__global__ __launch_bounds__(256)
void k_topk_old(unsigned long long* __restrict__ cand,
                const unsigned int* __restrict__ counter,
                const int* __restrict__ idx_all,
                const float* __restrict__ decoded,
                float* __restrict__ out,
                const int* __restrict__ top_k_p) {
  const int M = (int)*counter;
  const int K = *top_k_p;
  __shared__ unsigned long long wmin[4];
  __shared__ unsigned long long sbest;
  const int tid = threadIdx.x;

  for (int r = 0; r < K; ++r) {
    unsigned long long lmin = ~0ULL;
    for (int j = tid; j < M; j += 256) {
      unsigned long long v = cand[j];
      if (v < lmin) lmin = v;
    }
    #pragma unroll
    for (int off = 32; off > 0; off >>= 1) {
      unsigned long long o = shfl_down_u64(lmin, off);
      if (o < lmin) lmin = o;
    }
    if ((tid & 63) == 0) wmin[tid >> 6] = lmin;
    __syncthreads();
    if (tid == 0) {
      unsigned long long b = wmin[0];
      #pragma unroll
      for (int w = 1; w < 4; ++w) if (wmin[w] < b) b = wmin[w];
      sbest = b;
    }
    __syncthreads();
    unsigned long long b = sbest;
    if (b != ~0ULL) {
      for (int j = tid; j < M; j += 256)
        if (cand[j] == b) cand[j] = ~0ULL;
    }
    if (tid == 0) {
      if (b != ~0ULL) {
        unsigned int flat = (unsigned int)(b & 0xFFFFFFFFu);
        float score = key_to_float((unsigned int)(b >> 32));
        int cls = (int)(flat >> 11);
        int orig = idx_all[flat];
        out[r * 4 + 0] = decoded[orig * 4 + 0];
        out[r * 4 + 1] = decoded[orig * 4 + 1];
        out[r * 4 + 2] = decoded[orig * 4 + 2];
        out[r * 4 + 3] = decoded[orig * 4 + 3];
        out[K * 4 + r] = (float)(cls + 1);
        out[K * 5 + r] = score;
      } else {
        out[r * 4 + 0] = 0.0f; out[r * 4 + 1] = 0.0f;
        out[r * 4 + 2] = 1.0f; out[r * 4 + 3] = 1.0f;
        out[K * 4 + r] = 0.0f;
        out[K * 5 + r] = 0.0f;
      }
    }
    __syncthreads();
  }
}

// ---- launch ---------------------------------------------------------------
extern "C" void kernel_launch(void* const* d_in, const int* in_sizes, int n_in,
                              void* d_out, int out_size, void* d_ws, size_t ws_size,
                              hipStream_t stream) {
  const float* rois        = (const float*)d_in[0];
  const float* locs        = (const float*)d_in[1];
  const float* scores      = (const float*)d_in[2];
  const float* min_score   = (const float*)d_in[3];
  const float* max_overlap = (const float*)d_in[4];
  const int*   top_k       = (const int*)d_in[5];

  char* ws = (char*)d_ws;

  // new-path layout
  const size_t off_nvalid  = 0;                              // int[32] (also old counter)
  const size_t off_probs   = 256;                            // 2048*21*4 = 172032
  const size_t off_decoded = off_probs + NROI * NCLS * 4;    // 32768
  const size_t off_skey    = off_decoded + NROI * 4 * 4;     // 20*2048*8 = 327680
  const size_t off_sbox    = off_skey + (size_t)NFG * NROI * 8;      // 655360
  const size_t off_cand    = off_sbox + (size_t)NFG * NROI * 4 * 4;  // 20480
  const size_t off_mask    = off_cand + (size_t)CTOT * 8;    // 10485760
  const size_t needed      = off_mask + (size_t)NFG * NROI * 32 * 8;

  unsigned int* counter = (unsigned int*)(ws + off_nvalid);
  int*   nvalid  = (int*)(ws + off_nvalid);
  float* probs   = (float*)(ws + off_probs);
  float* decoded = (float*)(ws + off_decoded);
  unsigned long long* skey = (unsigned long long*)(ws + off_skey);
  float* sbox    = (float*)(ws + off_sbox);
  unsigned long long* cand = (unsigned long long*)(ws + off_cand);
  unsigned long long* mask = (unsigned long long*)(ws + off_mask);

  k_decode<<<NROI / 256, 256, 0, stream>>>(rois, locs, scores, probs, decoded, counter);

  if (ws_size >= needed) {
    k_sort<<<NFG, 256, 0, stream>>>(probs, decoded, min_score, skey, sbox, nvalid, cand);
    k_mask<<<NFG * 256, 256, 0, stream>>>(sbox, max_overlap, nvalid, mask);
    k_sweep<<<NFG, 64, 0, stream>>>(mask, skey, nvalid, cand);
    k_topk2<<<1, 256, 0, stream>>>(cand, sbox, (float*)d_out, top_k);
  } else {
    // fallback: round-1 path (fits in ~0.72 MB of ws)
    int* idx_all = (int*)(ws + off_skey);                    // reuse region
    unsigned long long* cand_old =
        (unsigned long long*)(ws + off_skey + (size_t)NFG * NROI * 4);
    k_nms_old<<<NFG, 256, 0, stream>>>(probs, decoded, min_score, max_overlap,
                                       idx_all, cand_old, counter);
    k_topk_old<<<1, 256, 0, stream>>>(cand_old, counter, idx_all, decoded,
                                      (float*)d_out, top_k);
  }
}

// Round 3
// 318.030 us; speedup vs baseline: 5.0843x; 1.3272x over previous
//
#include <hip/hip_runtime.h>
#include <cstdint>

#define NROI 2048
#define NCLS 21
#define NFG  20
#define CPAD 128          // survivors kept per class (>= top_k=100)
#define CTOT (NFG * CPAD) // 2560
#define CSRT 4096         // bitonic size for final top-k sort

typedef unsigned long long u64;
typedef unsigned int u32;

// ---- sortable key helpers -------------------------------------------------
// desc_key(s): larger float -> smaller uint, so ascending u64 sort ==
// (score descending, index ascending) when index is in the low 32 bits.
__device__ __forceinline__ u32 desc_key(float s) {
  u32 u = __float_as_uint(s);
  u32 asc = (u & 0x80000000u) ? ~u : (u | 0x80000000u);
  return ~asc;
}
__device__ __forceinline__ float key_to_float(u32 desc) {
  u32 asc = ~desc;
  u32 u = (asc & 0x80000000u) ? (asc ^ 0x80000000u) : ~asc;
  return __uint_as_float(u);
}

// ---- phase 1: softmax + argmax + box decode -------------------------------
__global__ __launch_bounds__(256)
void k_decode(const float* __restrict__ rois,
              const float* __restrict__ locs,
              const float* __restrict__ scores,
              float* __restrict__ probsT,     // [NCLS][NROI] transposed
              float* __restrict__ decoded) {
  int r = blockIdx.x * blockDim.x + threadIdx.x;
  if (r >= NROI) return;

  float s[NCLS];
  float m = scores[r * NCLS];
  #pragma unroll
  for (int c = 0; c < NCLS; ++c) { s[c] = scores[r * NCLS + c]; m = fmaxf(m, s[c]); }
  float e[NCLS]; float sum = 0.0f;
  #pragma unroll
  for (int c = 0; c < NCLS; ++c) { e[c] = expf(s[c] - m); sum += e[c]; }

  float p0 = e[0] / sum;
  probsT[r] = p0;
  int best = 0; float pb = p0;
  #pragma unroll
  for (int c = 1; c < NCLS; ++c) {
    float p = e[c] / sum;
    probsT[c * NROI + r] = p;
    if (p > pb) { pb = p; best = c; }   // strict > keeps first index (argmax semantics)
  }

  float x0 = rois[r * 4 + 0], y0 = rois[r * 4 + 1];
  float x1 = rois[r * 4 + 2], y1 = rois[r * 4 + 3];
  float pcx = __fmul_rn(__fadd_rn(x0, x1), 0.5f);
  float pcy = __fmul_rn(__fadd_rn(y0, y1), 0.5f);
  float pw  = __fsub_rn(x1, x0);
  float ph  = __fsub_rn(y1, y0);

  const float* g = locs + r * (NCLS * 4) + best * 4;
  float g0 = g[0] / 10.0f;
  float g1 = g[1] / 10.0f;
  float g2 = g[2] / 20.0f;
  float g3 = g[3] / 20.0f;

  // no-FMA-contraction decode to match numpy rounding
  float cx = __fadd_rn(__fmul_rn(g0, pw), pcx);
  float cy = __fadd_rn(__fmul_rn(g1, ph), pcy);
  float w  = __fmul_rn(expf(g2), pw);
  float h  = __fmul_rn(expf(g3), ph);
  float hw = __fmul_rn(w, 0.5f);
  float hh = __fmul_rn(h, 0.5f);
  decoded[r * 4 + 0] = __fsub_rn(cx, hw);
  decoded[r * 4 + 1] = __fsub_rn(cy, hh);
  decoded[r * 4 + 2] = __fadd_rn(cx, hw);
  decoded[r * 4 + 3] = __fadd_rn(cy, hh);
}

// ---- phase 2: fused per-class sort + greedy NMS + compact -----------------
// one block of 256 threads (4 waves) per foreground class.
__global__ __launch_bounds__(256)
void k_nms_fused(const float* __restrict__ probsT,
                 const float* __restrict__ decoded,
                 const float* __restrict__ min_score_p,
                 const float* __restrict__ max_overlap_p,
                 u64* __restrict__ cand,
                 float* __restrict__ cbox) {
  __shared__ u64 keys[NROI];                         // 16 KB
  __shared__ float sx0[NROI], sy0[NROI], sx1[NROI], sy1[NROI]; // 32 KB
  __shared__ u32 rem32[NROI / 32];                   // 256 B removed bitmap
  __shared__ int survLds[CPAD];                      // 512 B
  __shared__ u64 aliveShared;
  __shared__ int scountLds;
  __shared__ int cntLds;

  const int cls = blockIdx.x;
  const int tid = threadIdx.x;
  const int lane = tid & 63;
  const int wid = tid >> 6;
  const float msc = *min_score_p;
  const float ovr = *max_overlap_p;

  if (tid == 0) { cntLds = 0; scountLds = 0; }
  __syncthreads();

  // build keys from this class's prob column (contiguous 8 KB)
  int local = 0;
  for (int i = tid; i < NROI; i += 256) {
    float s = probsT[(cls + 1) * NROI + i];
    bool valid = s > msc;
    local += valid ? 1 : 0;
    float keyf = valid ? s : -__builtin_inff();
    keys[i] = ((u64)desc_key(keyf) << 32) | (u32)i;
  }
  atomicAdd(&cntLds, local);
  __syncthreads();

  // bitonic sort ascending => score desc, orig index asc (stable-equivalent)
  for (int k = 2; k <= NROI; k <<= 1) {
    for (int j = k >> 1; j > 0; j >>= 1) {
      for (int i = tid; i < NROI; i += 256) {
        int ixj = i ^ j;
        if (ixj > i) {
          u64 a = keys[i], b = keys[ixj];
          bool up = ((i & k) == 0);
          if ((a > b) == up) { keys[i] = b; keys[ixj] = a; }
        }
      }
      __syncthreads();
    }
  }

  // gather boxes into sorted order; init removed bitmap (rows >= nvalid dead)
  const int nv = cntLds;
  for (int i = tid; i < NROI; i += 256) {
    int orig = (int)(keys[i] & 0xFFFFFFFFu);
    sx0[i] = decoded[orig * 4 + 0];
    sy0[i] = decoded[orig * 4 + 1];
    sx1[i] = decoded[orig * 4 + 2];
    sy1[i] = decoded[orig * 4 + 3];
  }
  for (int w = tid; w < NROI / 32; w += 256) {
    int start = nv - w * 32;
    rem32[w] = (start <= 0) ? 0xFFFFFFFFu : ((start >= 32) ? 0u : (0xFFFFFFFFu << start));
  }
  __syncthreads();

  int sc = 0;
  for (int g = 0; g < NROI / 64; ++g) {
    // ---- intra-group resolve: wave 0 only, all in registers ----
    if (wid == 0) {
      u64 word = ((u64)rem32[2 * g + 1] << 32) | (u64)rem32[2 * g];
      u64 alive = ~word;
      int row = g * 64 + lane;
      float jx0 = sx0[row], jy0 = sy0[row], jx1 = sx1[row], jy1 = sy1[row];
      float areaj = __fmul_rn(__fsub_rn(jx1, jx0), __fsub_rn(jy1, jy0));
      u64 pend = alive;
      while (pend) {
        int i = __ffsll((long long)pend) - 1;
        pend &= pend - 1;
        if (!((alive >> i) & 1ULL)) continue;    // killed since queued
        float ix0 = __shfl(jx0, i), iy0 = __shfl(jy0, i);
        float ix1 = __shfl(jx1, i), iy1 = __shfl(jy1, i);
        float ia  = __shfl(areaj, i);
        float lx = fmaxf(ix0, jx0), ly = fmaxf(iy0, jy0);
        float rx = fminf(ix1, jx1), ry = fminf(iy1, jy1);
        float w_ = fmaxf(__fsub_rn(rx, lx), 0.0f);
        float h_ = fmaxf(__fsub_rn(ry, ly), 0.0f);
        float inter = __fmul_rn(w_, h_);
        float iou = __fdiv_rn(inter, __fsub_rn(__fadd_rn(ia, areaj), inter));
        bool kill = (lane > i) && (iou > ovr);
        u64 bal = __ballot(kill);
        alive &= ~bal;
        pend  &= ~bal;
      }
      // append survivors in position order (capped at CPAD)
      int base = sc;
      if ((alive >> lane) & 1ULL) {
        int rank = base + __popcll(alive & ((1ULL << lane) - 1ULL));
        if (rank < CPAD) survLds[rank] = row;
      }
      sc = base + __popcll(alive);
      if (lane == 0) { scountLds = sc; aliveShared = alive; }
    }
    __syncthreads();
    u64 aw = aliveShared;
    sc = scountLds;
    if (sc >= CPAD) break;   // uniform: later survivors can't reach global top-k

    // ---- suppress later columns by this group's survivors (all waves) ----
    if (aw) {
      const int colbase = (g + 1) * 64;
      float cx0[8], cy0[8], cx1[8], cy1[8], car[8];
      #pragma unroll
      for (int m = 0; m < 8; ++m) {
        int j = colbase + m * 256 + tid;
        if (j < NROI) {
          cx0[m] = sx0[j]; cy0[m] = sy0[j]; cx1[m] = sx1[j]; cy1[m] = sy1[j];
          car[m] = __fmul_rn(__fsub_rn(cx1[m], cx0[m]), __fsub_rn(cy1[m], cy0[m]));
        }
      }
      u32 supm = 0;
      u64 t = aw;
      while (t) {
        int b = __ffsll((long long)t) - 1;
        t &= t - 1;
        int i = g * 64 + b;
        float ix0 = sx0[i], iy0 = sy0[i], ix1 = sx1[i], iy1 = sy1[i]; // broadcast reads
        float ia = __fmul_rn(__fsub_rn(ix1, ix0), __fsub_rn(iy1, iy0));
        #pragma unroll
        for (int m = 0; m < 8; ++m) {
          int j = colbase + m * 256 + tid;
          if (j < NROI) {
            float lx = fmaxf(ix0, cx0[m]), ly = fmaxf(iy0, cy0[m]);
            float rx = fminf(ix1, cx1[m]), ry = fminf(iy1, cy1[m]);
            float w_ = fmaxf(__fsub_rn(rx, lx), 0.0f);
            float h_ = fmaxf(__fsub_rn(ry, ly), 0.0f);
            float inter = __fmul_rn(w_, h_);
            float iou = __fdiv_rn(inter, __fsub_rn(__fadd_rn(ia, car[m]), inter));
            if (iou > ovr) supm |= (1u << m);
          }
        }
      }
      #pragma unroll
      for (int m = 0; m < 8; ++m) {
        int j0 = colbase + m * 256 + (tid & ~63);   // wave's first column, wave-uniform
        if (j0 < NROI) {
          u64 bal = __ballot((supm >> m) & 1u);
          if (lane == 0) {
            int w0 = j0 >> 5;
            u32 lo = (u32)bal, hi = (u32)(bal >> 32);
            if (lo) atomicOr(&rem32[w0], lo);
            if (hi) atomicOr(&rem32[w0 + 1], hi);
          }
        }
      }
    }
    __syncthreads();   // suppression visible before next group's intra read
  }
  __syncthreads();

  // ---- compact output: per-class survivor list (sorted) ----
  sc = scountLds;
  if (sc > CPAD) sc = CPAD;
  for (int r = tid; r < CPAD; r += 256) {
    size_t o = (size_t)(cls * CPAD + r);
    if (r < sc) {
      int pos = survLds[r];
      u64 key = keys[pos];
      cand[o] = (key & 0xFFFFFFFF00000000ULL) | (u32)o;  // low32 order == flat-index order
      cbox[o * 4 + 0] = sx0[pos];
      cbox[o * 4 + 1] = sy0[pos];
      cbox[o * 4 + 2] = sx1[pos];
      cbox[o * 4 + 3] = sy1[pos];
    } else {
      cand[o] = ~0ULL;
    }
  }
}

// ---- phase 3: sort 2560 candidates, emit top-K ----------------------------
__global__ __launch_bounds__(256)
void k_topk2(const u64* __restrict__ cand,
             const float* __restrict__ cbox,
             float* __restrict__ out,
             const int* __restrict__ top_k_p) {
  __shared__ u64 keys[CSRT];   // 32 KB
  const int tid = threadIdx.x;
  for (int t = tid; t < CSRT; t += 256)
    keys[t] = (t < CTOT) ? cand[t] : ~0ULL;
  __syncthreads();

  for (int k = 2; k <= CSRT; k <<= 1) {
    for (int j = k >> 1; j > 0; j >>= 1) {
      for (int t = tid; t < CSRT; t += 256) {
        int ixj = t ^ j;
        if (ixj > t) {
          u64 a = keys[t], b = keys[ixj];
          bool up = ((t & k) == 0);
          if ((a > b) == up) { keys[t] = b; keys[ixj] = a; }
        }
      }
      __syncthreads();
    }
  }

  const int K = *top_k_p;
  for (int r = tid; r < K; r += 256) {
    u64 key = keys[r];
    if (key != ~0ULL) {
      u32 flat = (u32)(key & 0xFFFFFFFFu);
      float score = key_to_float((u32)(key >> 32));
      int cls = (int)(flat >> 7);              // / CPAD
      out[r * 4 + 0] = cbox[(size_t)flat * 4 + 0];
      out[r * 4 + 1] = cbox[(size_t)flat * 4 + 1];
      out[r * 4 + 2] = cbox[(size_t)flat * 4 + 2];
      out[r * 4 + 3] = cbox[(size_t)flat * 4 + 3];
      out[K * 4 + r] = (float)(cls + 1);
      out[K * 5 + r] = score;
    } else {
      out[r * 4 + 0] = 0.0f; out[r * 4 + 1] = 0.0f;
      out[r * 4 + 2] = 1.0f; out[r * 4 + 3] = 1.0f;
      out[K * 4 + r] = 0.0f;
      out[K * 5 + r] = 0.0f;
    }
  }
}

// ---- launch ---------------------------------------------------------------
extern "C" void kernel_launch(void* const* d_in, const int* in_sizes, int n_in,
                              void* d_out, int out_size, void* d_ws, size_t ws_size,
                              hipStream_t stream) {
  const float* rois        = (const float*)d_in[0];
  const float* locs        = (const float*)d_in[1];
  const float* scores      = (const float*)d_in[2];
  const float* min_score   = (const float*)d_in[3];
  const float* max_overlap = (const float*)d_in[4];
  const int*   top_k       = (const int*)d_in[5];

  char* ws = (char*)d_ws;
  // layout: probsT 21*2048*4 | decoded 2048*4*4 | cand 2560*8 | cbox 2560*4*4
  const size_t off_probsT  = 0;
  const size_t off_decoded = off_probsT + (size_t)NCLS * NROI * 4;   // 172032
  const size_t off_cand    = off_decoded + (size_t)NROI * 4 * 4;     // +32768
  const size_t off_cbox    = off_cand + (size_t)CTOT * 8;            // +20480
  float* probsT  = (float*)(ws + off_probsT);
  float* decoded = (float*)(ws + off_decoded);
  u64*   cand    = (u64*)(ws + off_cand);
  float* cbox    = (float*)(ws + off_cbox);

  k_decode<<<NROI / 256, 256, 0, stream>>>(rois, locs, scores, probsT, decoded);
  k_nms_fused<<<NFG, 256, 0, stream>>>(probsT, decoded, min_score, max_overlap, cand, cbox);
  k_topk2<<<1, 256, 0, stream>>>(cand, cbox, (float*)d_out, top_k);
}

// Round 4
// 122.186 us; speedup vs baseline: 13.2337x; 2.6028x over previous
//
#include <hip/hip_runtime.h>
#include <cstdint>

#define NROI 2048
#define NCLS 21
#define NFG  20
#define CPAD 128          // survivors kept per class (>= top_k=100)
#define CTOT (NFG * CPAD) // 2560
#define NTHR 1024         // threads per NMS block (16 waves)

typedef unsigned long long u64;
typedef unsigned int u32;

// ---- sortable key helpers -------------------------------------------------
// desc_key(s): larger float -> smaller uint, so ascending u64 sort ==
// (score descending, index ascending) when index is in the low 32 bits.
__device__ __forceinline__ u32 desc_key(float s) {
  u32 u = __float_as_uint(s);
  u32 asc = (u & 0x80000000u) ? ~u : (u | 0x80000000u);
  return ~asc;
}
__device__ __forceinline__ float key_to_float(u32 desc) {
  u32 asc = ~desc;
  u32 u = (asc & 0x80000000u) ? (asc ^ 0x80000000u) : ~asc;
  return __uint_as_float(u);
}
__device__ __forceinline__ u64 shfl_u64(u64 v, int src) {
  u32 lo = (u32)(v & 0xFFFFFFFFull);
  u32 hi = (u32)(v >> 32);
  lo = __shfl(lo, src);
  hi = __shfl(hi, src);
  return ((u64)hi << 32) | (u64)lo;
}

// ---- fused per-class: softmax keys -> sort -> decode -> greedy NMS --------
// one block of 1024 threads (16 waves) per foreground class.
__global__ __launch_bounds__(NTHR)
void k_nms(const float* __restrict__ rois,
           const float* __restrict__ locs,
           const float* __restrict__ scores,
           const float* __restrict__ min_score_p,
           const float* __restrict__ max_overlap_p,
           u64* __restrict__ cand,
           float4* __restrict__ cbox) {
  __shared__ u64 keys[NROI];        // 16 KB
  __shared__ float4 sbox[NROI];     // 32 KB (sorted boxes: x0,y0,x1,y1)
  __shared__ u32 rem32[NROI / 32];  // 256 B removed bitmap (sorted order)
  __shared__ u32 gm32[128];         // 512 B group 64x64 suppression matrix
  __shared__ int survLds[CPAD];     // 512 B
  __shared__ u64 aliveShared;
  __shared__ int scountLds, cntLds;

  const int cls = blockIdx.x;
  const int cc = cls + 1;           // prob column
  const int tid = threadIdx.x;
  const int lane = tid & 63;
  const int wid = tid >> 6;
  const float msc = *min_score_p;
  const float ovr = *max_overlap_p;

  if (tid == 0) { cntLds = 0; scountLds = 0; }
  __syncthreads();

  // ---- phase 0: softmax prob for this class -> keys (orig order) ----
  int local = 0;
  for (int r = tid; r < NROI; r += NTHR) {
    const float* sr = scores + r * NCLS;
    float s[NCLS];
    #pragma unroll
    for (int c = 0; c < NCLS; ++c) s[c] = sr[c];
    float m = s[0];
    #pragma unroll
    for (int c = 0; c < NCLS; ++c) m = fmaxf(m, s[c]);
    float sum = 0.0f;
    #pragma unroll
    for (int c = 0; c < NCLS; ++c) { s[c] = expf(s[c] - m); sum += s[c]; }
    float ec = s[0];
    #pragma unroll
    for (int c = 1; c < NCLS; ++c) ec = (c == cc) ? s[c] : ec;  // static idx only
    float p = ec / sum;               // identical to e[c]/sum in reference path
    bool valid = p > msc;
    local += valid ? 1 : 0;
    float keyf = valid ? p : -__builtin_inff();
    keys[r] = ((u64)desc_key(keyf) << 32) | (u32)r;
  }
  atomicAdd(&cntLds, local);
  __syncthreads();

  // ---- bitonic sort: exactly one pair per thread per pass ----
  for (int k = 2; k <= NROI; k <<= 1) {
    for (int j = k >> 1; j > 0; j >>= 1) {
      int lo = tid & (j - 1);
      int i = ((tid & ~(j - 1)) << 1) | lo;
      int ixj = i | j;
      u64 a = keys[i], b = keys[ixj];
      bool up = ((i & k) == 0);
      if ((a > b) == up) { keys[i] = b; keys[ixj] = a; }
      __syncthreads();
    }
  }

  const int nv = cntLds;

  // ---- gather: recompute argmax + decode into sorted order ----
  for (int i = tid; i < NROI; i += NTHR) {
    int orig = (int)(keys[i] & 0xFFFFFFFFu);
    const float* sr = scores + orig * NCLS;
    float s[NCLS];
    #pragma unroll
    for (int c = 0; c < NCLS; ++c) s[c] = sr[c];
    float m = s[0];
    #pragma unroll
    for (int c = 0; c < NCLS; ++c) m = fmaxf(m, s[c]);
    float sum = 0.0f;
    #pragma unroll
    for (int c = 0; c < NCLS; ++c) { s[c] = expf(s[c] - m); sum += s[c]; }
    float pb = s[0] / sum; int best = 0;
    #pragma unroll
    for (int c = 1; c < NCLS; ++c) {
      float p = s[c] / sum;
      if (p > pb) { pb = p; best = c; }  // strict > == first-index argmax
    }

    float x0 = rois[orig * 4 + 0], y0 = rois[orig * 4 + 1];
    float x1 = rois[orig * 4 + 2], y1 = rois[orig * 4 + 3];
    float pcx = __fmul_rn(__fadd_rn(x0, x1), 0.5f);
    float pcy = __fmul_rn(__fadd_rn(y0, y1), 0.5f);
    float pw  = __fsub_rn(x1, x0);
    float ph  = __fsub_rn(y1, y0);

    const float* gp = locs + orig * (NCLS * 4) + best * 4;
    float g0 = gp[0] / 10.0f;
    float g1 = gp[1] / 10.0f;
    float g2 = gp[2] / 20.0f;
    float g3 = gp[3] / 20.0f;

    float cx = __fadd_rn(__fmul_rn(g0, pw), pcx);
    float cy = __fadd_rn(__fmul_rn(g1, ph), pcy);
    float w  = __fmul_rn(expf(g2), pw);
    float h  = __fmul_rn(expf(g3), ph);
    float hw = __fmul_rn(w, 0.5f);
    float hh = __fmul_rn(h, 0.5f);
    sbox[i] = make_float4(__fsub_rn(cx, hw), __fsub_rn(cy, hh),
                          __fadd_rn(cx, hw), __fadd_rn(cy, hh));
  }
  for (int w = tid; w < NROI / 32; w += NTHR) {
    int start = nv - w * 32;
    rem32[w] = (start <= 0) ? 0xFFFFFFFFu : ((start >= 32) ? 0u : (0xFFFFFFFFu << start));
  }
  __syncthreads();

  // ---- greedy NMS in 64-row groups ----
  int sc = 0;
  const int ng = (nv + 63) >> 6;
  for (int g = 0; g < ng; ++g) {
    // build 64x64 IoU bit matrix in parallel (4 cells per thread)
    if (tid < 128) gm32[tid] = 0;
    __syncthreads();
    {
      const int i = tid >> 4;               // row within group
      const int c0 = (tid & 15) << 2;       // 4 cols within group
      float4 bi = sbox[(g << 6) + i];
      float ia = __fmul_rn(__fsub_rn(bi.z, bi.x), __fsub_rn(bi.w, bi.y));
      u32 nib = 0;
      #pragma unroll
      for (int q = 0; q < 4; ++q) {
        int jj = c0 + q;
        if (jj > i) {
          float4 bj = sbox[(g << 6) + jj];
          float lx = fmaxf(bi.x, bj.x), ly = fmaxf(bi.y, bj.y);
          float rx = fminf(bi.z, bj.z), ry = fminf(bi.w, bj.w);
          float w_ = fmaxf(__fsub_rn(rx, lx), 0.0f);
          float h_ = fmaxf(__fsub_rn(ry, ly), 0.0f);
          float inter = __fmul_rn(w_, h_);
          float ab = __fmul_rn(__fsub_rn(bj.z, bj.x), __fsub_rn(bj.w, bj.y));
          float iou = __fdiv_rn(inter, __fsub_rn(__fadd_rn(ia, ab), inter));
          if (iou > ovr) nib |= (1u << (jj & 31));
        }
      }
      if (nib) atomicOr(&gm32[(i << 1) + (c0 >> 5)], nib);
    }
    __syncthreads();

    // greedy closure over the 64-bit group (wave 0)
    if (wid == 0) {
      u64 mrow = ((u64)gm32[(lane << 1) + 1] << 32) | (u64)gm32[lane << 1];
      u64 alive = ~(((u64)rem32[(g << 1) + 1] << 32) | (u64)rem32[g << 1]);
      u64 pend = alive;
      while (pend) {
        int i = __ffsll((long long)pend) - 1;   // always still alive (invariant)
        pend &= pend - 1;
        u64 mi = shfl_u64(mrow, i);             // bits > i only
        alive &= ~mi;
        pend  &= ~mi;
      }
      int base = sc;
      if ((alive >> lane) & 1ULL) {
        int rank = base + __popcll(alive & ((1ULL << lane) - 1ULL));
        if (rank < CPAD) survLds[rank] = (g << 6) + lane;
      }
      sc = base + __popcll(alive);
      if (lane == 0) { scountLds = sc; aliveShared = alive; }
    }
    __syncthreads();
    u64 aw = aliveShared;
    sc = scountLds;
    if (sc >= CPAD) break;    // uniform; later survivors can't reach global top-k

    // suppress later columns by this group's survivors (2 cols per thread)
    const int colbase = (g + 1) << 6;
    if (aw != 0ULL && colbase < nv) {
      #pragma unroll
      for (int ss = 0; ss < 2; ++ss) {
        int j = colbase + ss * NTHR + tid;
        bool inr = j < nv;
        bool act = false;
        float4 bj; float ab = 0.0f;
        if (inr) {
          act = !((rem32[j >> 5] >> (j & 31)) & 1u);
          bj = sbox[j];
          ab = __fmul_rn(__fsub_rn(bj.z, bj.x), __fsub_rn(bj.w, bj.y));
        }
        bool kill = false;
        u64 t = aw;                       // wave-uniform loop
        while (t) {
          int b = __ffsll((long long)t) - 1;
          t &= t - 1;
          float4 bi = sbox[(g << 6) + b]; // LDS broadcast
          if (act && !kill) {
            float ia = __fmul_rn(__fsub_rn(bi.z, bi.x), __fsub_rn(bi.w, bi.y));
            float lx = fmaxf(bi.x, bj.x), ly = fmaxf(bi.y, bj.y);
            float rx = fminf(bi.z, bj.z), ry = fminf(bi.w, bj.w);
            float w_ = fmaxf(__fsub_rn(rx, lx), 0.0f);
            float h_ = fmaxf(__fsub_rn(ry, ly), 0.0f);
            float inter = __fmul_rn(w_, h_);
            float iou = __fdiv_rn(inter, __fsub_rn(__fadd_rn(ia, ab), inter));
            kill = iou > ovr;
          }
        }
        u64 bal = __ballot(kill);
        if (lane == 0 && bal != 0ULL) {
          int j0 = colbase + ss * NTHR + (wid << 6);   // 64-aligned wave base
          u32 loB = (u32)bal, hiB = (u32)(bal >> 32);
          if (loB) atomicOr(&rem32[j0 >> 5], loB);
          if (hiB) atomicOr(&rem32[(j0 >> 5) + 1], hiB);
        }
      }
    }
    __syncthreads();
  }

  // ---- emit per-class survivor list (already in sorted order) ----
  int scf = scountLds; if (scf > CPAD) scf = CPAD;
  if (tid < CPAD) {
    int o = cls * CPAD + tid;
    if (tid < scf) {
      int pos = survLds[tid];
      u64 key = keys[pos];
      cand[o] = (key & 0xFFFFFFFF00000000ULL) | (u32)o; // low32 == global tie-order
      cbox[o] = sbox[pos];
    } else {
      cand[o] = ~0ULL;
    }
  }
}

// ---- final top-K by rank selection (keys unique -> ranks unique) ----------
__global__ __launch_bounds__(256)
void k_topk(const u64* __restrict__ cand,
            const float4* __restrict__ cbox,
            float* __restrict__ out,
            const int* __restrict__ top_k_p) {
  __shared__ u64 kk[CTOT];     // 20 KB
  __shared__ int mSh;
  const int tid = threadIdx.x;
  if (tid == 0) mSh = 0;
  __syncthreads();
  int np = 0;
  for (int t = tid; t < CTOT; t += 256) {
    u64 v = cand[t];
    kk[t] = v;
    np += (v != ~0ULL) ? 1 : 0;
  }
  atomicAdd(&mSh, np);
  __syncthreads();
  const int M = mSh;           // total survivors across classes
  const int K = *top_k_p;

  const int gidx = blockIdx.x * 256 + tid;   // grid covers CTOT exactly
  u64 mykey = kk[gidx];
  if (mykey != ~0ULL) {
    int rank = 0;
    for (int j = 0; j < CTOT; j += 8) {
      #pragma unroll
      for (int q = 0; q < 8; ++q) rank += (kk[j + q] < mykey) ? 1 : 0;
    }
    if (rank < K) {
      u32 flat = (u32)(mykey & 0xFFFFFFFFu);
      float score = key_to_float((u32)(mykey >> 32));
      int cls = (int)(flat >> 7);            // / CPAD
      float4 b = cbox[flat];
      out[rank * 4 + 0] = b.x;
      out[rank * 4 + 1] = b.y;
      out[rank * 4 + 2] = b.z;
      out[rank * 4 + 3] = b.w;
      out[K * 4 + rank] = (float)(cls + 1);
      out[K * 5 + rank] = score;
    }
  }
  if (blockIdx.x == 0) {
    for (int r = tid; r < K; r += 256) {
      if (r >= M) {
        out[r * 4 + 0] = 0.0f; out[r * 4 + 1] = 0.0f;
        out[r * 4 + 2] = 1.0f; out[r * 4 + 3] = 1.0f;
        out[K * 4 + r] = 0.0f;
        out[K * 5 + r] = 0.0f;
      }
    }
  }
}

// ---- launch ---------------------------------------------------------------
extern "C" void kernel_launch(void* const* d_in, const int* in_sizes, int n_in,
                              void* d_out, int out_size, void* d_ws, size_t ws_size,
                              hipStream_t stream) {
  const float* rois        = (const float*)d_in[0];
  const float* locs        = (const float*)d_in[1];
  const float* scores      = (const float*)d_in[2];
  const float* min_score   = (const float*)d_in[3];
  const float* max_overlap = (const float*)d_in[4];
  const int*   top_k       = (const int*)d_in[5];

  char* ws = (char*)d_ws;
  // layout: cand 2560*8 | cbox 2560*16   (both 16B-aligned)
  u64*    cand = (u64*)ws;
  float4* cbox = (float4*)(ws + (size_t)CTOT * 8);

  k_nms<<<NFG, NTHR, 0, stream>>>(rois, locs, scores, min_score, max_overlap,
                                  cand, cbox);
  k_topk<<<CTOT / 256, 256, 0, stream>>>(cand, cbox, (float*)d_out, top_k);
}

// Round 5
// 109.567 us; speedup vs baseline: 14.7578x; 1.1152x over previous
//
#include <hip/hip_runtime.h>
#include <cstdint>

#define NROI 2048
#define NCLS 21
#define NFG  20
#define CPAD 128          // survivors kept per class (>= top_k=100)
#define CTOT (NFG * CPAD) // 2560
#define NTHR 1024         // threads per NMS block (16 waves)
#define DROWS 256         // rows per decode block

typedef unsigned long long u64;
typedef unsigned int u32;

// ---- sortable key helpers -------------------------------------------------
// desc_key(s): larger float -> smaller uint, so ascending u64 sort ==
// (score descending, index ascending) when index is in the low 32 bits.
__device__ __forceinline__ u32 desc_key(float s) {
  u32 u = __float_as_uint(s);
  u32 asc = (u & 0x80000000u) ? ~u : (u | 0x80000000u);
  return ~asc;
}
__device__ __forceinline__ float key_to_float(u32 desc) {
  u32 asc = ~desc;
  u32 u = (asc & 0x80000000u) ? (asc ^ 0x80000000u) : ~asc;
  return __uint_as_float(u);
}
__device__ __forceinline__ u64 shfl_u64(u64 v, int src) {
  u32 lo = (u32)(v & 0xFFFFFFFFull);
  u32 hi = (u32)(v >> 32);
  lo = __shfl(lo, src);
  hi = __shfl(hi, src);
  return ((u64)hi << 32) | (u64)lo;
}

// ---- phase 1: coalesced softmax + argmax + decode -------------------------
__global__ __launch_bounds__(256)
void k_decode(const float* __restrict__ rois,
              const float* __restrict__ locs,
              const float* __restrict__ scores,
              float* __restrict__ probsT,     // [NFG][NROI]: class c+1 -> row c
              float4* __restrict__ decoded,
              u32* __restrict__ done) {
  __shared__ float srow[DROWS][NCLS + 2];   // stride 23 (odd) -> conflict-free
  const int tid = threadIdx.x;
  const int rbase = blockIdx.x * DROWS;
  if (rbase == 0 && tid == 0) *done = 0u;   // reset last-block counter each launch

  // coalesced staging of 256 score rows
  const float* src = scores + (size_t)rbase * NCLS;
  for (int t = tid; t < DROWS * NCLS; t += 256)
    srow[t / NCLS][t % NCLS] = src[t];
  __syncthreads();

  const int r = rbase + tid;
  float s[NCLS];
  #pragma unroll
  for (int c = 0; c < NCLS; ++c) s[c] = srow[tid][c];
  float m = s[0];
  #pragma unroll
  for (int c = 0; c < NCLS; ++c) m = fmaxf(m, s[c]);
  float sum = 0.0f;
  #pragma unroll
  for (int c = 0; c < NCLS; ++c) { s[c] = expf(s[c] - m); sum += s[c]; }

  float pb = s[0] / sum; int best = 0;
  #pragma unroll
  for (int c = 1; c < NCLS; ++c) {
    float p = s[c] / sum;
    probsT[(c - 1) * NROI + r] = p;        // coalesced store per class
    if (p > pb) { pb = p; best = c; }      // strict > == first-index argmax
  }

  float4 roi = ((const float4*)rois)[r];
  float pcx = __fmul_rn(__fadd_rn(roi.x, roi.z), 0.5f);
  float pcy = __fmul_rn(__fadd_rn(roi.y, roi.w), 0.5f);
  float pw  = __fsub_rn(roi.z, roi.x);
  float ph  = __fsub_rn(roi.w, roi.y);

  float4 gl = ((const float4*)locs)[r * NCLS + best];   // 16B-aligned
  float g0 = gl.x / 10.0f;
  float g1 = gl.y / 10.0f;
  float g2 = gl.z / 20.0f;
  float g3 = gl.w / 20.0f;

  // no-FMA-contraction decode to match numpy rounding
  float cx = __fadd_rn(__fmul_rn(g0, pw), pcx);
  float cy = __fadd_rn(__fmul_rn(g1, ph), pcy);
  float w  = __fmul_rn(expf(g2), pw);
  float h  = __fmul_rn(expf(g3), ph);
  float hw = __fmul_rn(w, 0.5f);
  float hh = __fmul_rn(h, 0.5f);
  decoded[r] = make_float4(__fsub_rn(cx, hw), __fsub_rn(cy, hh),
                           __fadd_rn(cx, hw), __fadd_rn(cy, hh));
}

// ---- phase 2: per-class sort + greedy NMS + last-block top-k --------------
__global__ __launch_bounds__(NTHR)
void k_nms(const float* __restrict__ probsT,
           const float4* __restrict__ decoded,
           const float* __restrict__ min_score_p,
           const float* __restrict__ max_overlap_p,
           u64* __restrict__ cand,
           float4* __restrict__ cbox,
           u32* __restrict__ done,
           float* __restrict__ out,
           const int* __restrict__ top_k_p) {
  __shared__ u64 keys[NROI];        // 16 KB
  __shared__ float4 sbox[NROI];     // 32 KB (reused as kk[2560] for topk)
  __shared__ u32 rem32[NROI / 32];  // removed bitmap (sorted order)
  __shared__ u32 gm32[128];         // group 64x64 suppression matrix
  __shared__ int survLds[CPAD];
  __shared__ u64 aliveShared;
  __shared__ int scountLds, cntLds;
  __shared__ u32 lastSh;

  const int cls = blockIdx.x;
  const int tid = threadIdx.x;
  const int lane = tid & 63;
  const int wid = tid >> 6;
  const float msc = *min_score_p;
  const float ovr = *max_overlap_p;

  if (tid == 0) { cntLds = 0; scountLds = 0; }
  __syncthreads();

  // ---- keys from this class's prob column (coalesced 8 KB) ----
  int local = 0;
  for (int i = tid; i < NROI; i += NTHR) {
    float p = probsT[cls * NROI + i];
    bool valid = p > msc;
    local += valid ? 1 : 0;
    float keyf = valid ? p : -__builtin_inff();
    keys[i] = ((u64)desc_key(keyf) << 32) | (u32)i;
  }
  atomicAdd(&cntLds, local);
  __syncthreads();

  // ---- bitonic sort: one pair/thread/pass; wave-local phases skip barrier --
  // For j<=64, wave w's pairs stay inside its private segment [128w,128w+128):
  // i(t)=((t&~(j-1))<<1)|(t&(j-1)). Full barrier only for cross-wave phases
  // (j>64) and at the cross->intra transition (j==64 && k>128).
  for (int k = 2; k <= NROI; k <<= 1) {
    for (int j = k >> 1; j > 0; j >>= 1) {
      if (j > 64 || (j == 64 && k > 128)) __syncthreads();
      else asm volatile("s_waitcnt lgkmcnt(0)" ::: "memory");
      int lo = tid & (j - 1);
      int i = ((tid & ~(j - 1)) << 1) | lo;
      int ixj = i | j;
      u64 a = keys[i], b = keys[ixj];
      bool up = ((i & k) == 0);
      if ((a > b) == up) { keys[i] = b; keys[ixj] = a; }
    }
  }
  __syncthreads();

  const int nv = cntLds;

  // ---- gather boxes into sorted order (scattered float4, cheap) ----
  for (int i = tid; i < NROI; i += NTHR) {
    int orig = (int)(keys[i] & 0xFFFFFFFFu);
    sbox[i] = decoded[orig];
  }
  for (int w = tid; w < NROI / 32; w += NTHR) {
    int start = nv - w * 32;
    rem32[w] = (start <= 0) ? 0xFFFFFFFFu : ((start >= 32) ? 0u : (0xFFFFFFFFu << start));
  }
  __syncthreads();

  // ---- greedy NMS in 64-row groups ----
  int sc = 0;
  const int ng = (nv + 63) >> 6;
  for (int g = 0; g < ng; ++g) {
    if (tid < 128) gm32[tid] = 0;
    __syncthreads();
    {
      const int i = tid >> 4;               // row within group
      const int c0 = (tid & 15) << 2;       // 4 cols within group
      float4 bi = sbox[(g << 6) + i];
      float ia = __fmul_rn(__fsub_rn(bi.z, bi.x), __fsub_rn(bi.w, bi.y));
      u32 nib = 0;
      #pragma unroll
      for (int q = 0; q < 4; ++q) {
        int jj = c0 + q;
        if (jj > i) {
          float4 bj = sbox[(g << 6) + jj];
          float lx = fmaxf(bi.x, bj.x), ly = fmaxf(bi.y, bj.y);
          float rx = fminf(bi.z, bj.z), ry = fminf(bi.w, bj.w);
          float w_ = fmaxf(__fsub_rn(rx, lx), 0.0f);
          float h_ = fmaxf(__fsub_rn(ry, ly), 0.0f);
          float inter = __fmul_rn(w_, h_);
          float ab = __fmul_rn(__fsub_rn(bj.z, bj.x), __fsub_rn(bj.w, bj.y));
          float iou = __fdiv_rn(inter, __fsub_rn(__fadd_rn(ia, ab), inter));
          if (iou > ovr) nib |= (1u << (jj & 31));
        }
      }
      if (nib) atomicOr(&gm32[(i << 1) + (c0 >> 5)], nib);
    }
    __syncthreads();

    // greedy closure over the 64-bit group (wave 0)
    if (wid == 0) {
      u64 mrow = ((u64)gm32[(lane << 1) + 1] << 32) | (u64)gm32[lane << 1];
      u64 alive = ~(((u64)rem32[(g << 1) + 1] << 32) | (u64)rem32[g << 1]);
      u64 pend = alive;
      while (pend) {
        int i = __ffsll((long long)pend) - 1;
        pend &= pend - 1;
        u64 mi = shfl_u64(mrow, i);          // bits > i only
        alive &= ~mi;
        pend  &= ~mi;
      }
      int base = sc;
      if ((alive >> lane) & 1ULL) {
        int rank = base + __popcll(alive & ((1ULL << lane) - 1ULL));
        if (rank < CPAD) survLds[rank] = (g << 6) + lane;
      }
      sc = base + __popcll(alive);
      if (lane == 0) { scountLds = sc; aliveShared = alive; }
    }
    __syncthreads();
    u64 aw = aliveShared;
    sc = scountLds;
    if (sc >= CPAD) break;    // uniform; later survivors can't reach global top-k

    // suppress later columns by this group's survivors (2 cols per thread)
    const int colbase = (g + 1) << 6;
    if (aw != 0ULL && colbase < nv) {
      #pragma unroll
      for (int ss = 0; ss < 2; ++ss) {
        int j = colbase + ss * NTHR + tid;
        bool inr = j < nv;
        bool act = false;
        float4 bj; float ab = 0.0f;
        if (inr) {
          act = !((rem32[j >> 5] >> (j & 31)) & 1u);
          bj = sbox[j];
          ab = __fmul_rn(__fsub_rn(bj.z, bj.x), __fsub_rn(bj.w, bj.y));
        }
        bool kill = false;
        u64 t = aw;                       // wave-uniform loop
        while (t) {
          int b = __ffsll((long long)t) - 1;
          t &= t - 1;
          float4 bi = sbox[(g << 6) + b]; // LDS broadcast
          if (act && !kill) {
            float ia = __fmul_rn(__fsub_rn(bi.z, bi.x), __fsub_rn(bi.w, bi.y));
            float lx = fmaxf(bi.x, bj.x), ly = fmaxf(bi.y, bj.y);
            float rx = fminf(bi.z, bj.z), ry = fminf(bi.w, bj.w);
            float w_ = fmaxf(__fsub_rn(rx, lx), 0.0f);
            float h_ = fmaxf(__fsub_rn(ry, ly), 0.0f);
            float inter = __fmul_rn(w_, h_);
            float iou = __fdiv_rn(inter, __fsub_rn(__fadd_rn(ia, ab), inter));
            kill = iou > ovr;
          }
        }
        u64 bal = __ballot(kill);
        if (lane == 0 && bal != 0ULL) {
          int j0 = colbase + ss * NTHR + (wid << 6);   // 64-aligned wave base
          u32 loB = (u32)bal, hiB = (u32)(bal >> 32);
          if (loB) atomicOr(&rem32[j0 >> 5], loB);
          if (hiB) atomicOr(&rem32[(j0 >> 5) + 1], hiB);
        }
      }
    }
    __syncthreads();
  }
  __syncthreads();

  // ---- emit per-class survivor list (sorted; segments strictly ascending) --
  int scf = scountLds; if (scf > CPAD) scf = CPAD;
  if (tid < CPAD) {
    int o = cls * CPAD + tid;
    if (tid < scf) {
      int pos = survLds[tid];
      u64 key = keys[pos];
      cand[o] = (key & 0xFFFFFFFF00000000ULL) | (u32)o; // low32 == global tie-order
      cbox[o] = sbox[pos];
    } else {
      cand[o] = ~0ULL;
    }
  }

  // ---- signal completion; last block does the global top-K ----
  __threadfence();                 // device-scope release of cand/cbox writes
  __syncthreads();
  if (tid == 0) lastSh = atomicAdd(done, 1u);
  __syncthreads();
  if (lastSh != NFG - 1) return;
  __threadfence();                 // acquire: see all blocks' cand/cbox

  u64* kk = (u64*)sbox;            // overlay (sbox no longer needed)
  if (tid == 0) cntLds = 0;
  __syncthreads();
  int np = 0;
  for (int t = tid; t < CTOT; t += NTHR) {
    u64 v = cand[t];
    kk[t] = v;
    np += (v != ~0ULL) ? 1 : 0;
  }
  atomicAdd(&cntLds, np);
  __syncthreads();
  const int M = cntLds;
  const int K = *top_k_p;

  // exact global rank via 20 per-class binary searches (keys unique)
  for (int t = tid; t < CTOT; t += NTHR) {
    u64 kap = kk[t];
    if (kap == ~0ULL) continue;
    int rank = 0;
    #pragma unroll
    for (int c = 0; c < NFG; ++c) {
      const u64* a = kk + c * CPAD;
      int lb = 0;
      #pragma unroll
      for (int s2 = CPAD >> 1; s2; s2 >>= 1) {
        int p = lb + s2;
        if (a[p - 1] < kap) lb = p;
      }
      rank += lb;                  // count of keys < kap in class c
    }
    if (rank < K) {
      u32 flat = (u32)(kap & 0xFFFFFFFFu);
      float score = key_to_float((u32)(kap >> 32));
      int c2 = (int)(flat >> 7);   // / CPAD
      float4 b = cbox[flat];
      out[rank * 4 + 0] = b.x;
      out[rank * 4 + 1] = b.y;
      out[rank * 4 + 2] = b.z;
      out[rank * 4 + 3] = b.w;
      out[K * 4 + rank] = (float)(c2 + 1);
      out[K * 5 + rank] = score;
    }
  }
  for (int r = tid; r < K; r += NTHR) {
    if (r >= M) {
      out[r * 4 + 0] = 0.0f; out[r * 4 + 1] = 0.0f;
      out[r * 4 + 2] = 1.0f; out[r * 4 + 3] = 1.0f;
      out[K * 4 + r] = 0.0f;
      out[K * 5 + r] = 0.0f;
    }
  }
}

// ---- launch ---------------------------------------------------------------
extern "C" void kernel_launch(void* const* d_in, const int* in_sizes, int n_in,
                              void* d_out, int out_size, void* d_ws, size_t ws_size,
                              hipStream_t stream) {
  const float* rois        = (const float*)d_in[0];
  const float* locs        = (const float*)d_in[1];
  const float* scores      = (const float*)d_in[2];
  const float* min_score   = (const float*)d_in[3];
  const float* max_overlap = (const float*)d_in[4];
  const int*   top_k       = (const int*)d_in[5];

  char* ws = (char*)d_ws;
  // layout: cand 2560*8 | cbox 2560*16 | probsT 20*2048*4 | decoded 2048*16 | done 4
  u64*    cand    = (u64*)ws;
  float4* cbox    = (float4*)(ws + 20480);
  float*  probsT  = (float*)(ws + 20480 + 40960);
  float4* decoded = (float4*)(ws + 20480 + 40960 + 163840);
  u32*    done    = (u32*)(ws + 20480 + 40960 + 163840 + 32768);

  k_decode<<<NROI / DROWS, 256, 0, stream>>>(rois, locs, scores, probsT, decoded, done);
  k_nms<<<NFG, NTHR, 0, stream>>>(probsT, decoded, min_score, max_overlap,
                                  cand, cbox, done, (float*)d_out, top_k);
}